// Round 10
// baseline (286.570 us; speedup 1.0000x reference)
//
#include <hip/hip_runtime.h>

// LSTM B=8192,T=256,I=1,H=50 via MFMA -- R10: fully-uniform waves.
// Per block: 16 batches, 13 waves (NTH=832), wave wv owns tile T=wv.
// Per step: D[208x16] = W_hh[208x64] x h[64x16]; rows = unit*4+gate
// (50 real units, rows j>=50 zero-padded), cols = batches. C/D layout: lane
// (lrow=ln&15, quad=ln>>4) of wave T gets gates (i,f,g,o) of
// (batch=lrow, unit=4T+quad) in its 4 acc regs -> activations in-register.
// x*W_ih and bias folded POST-MFMA via per-lane fp32 FMAs (no GEMM columns,
// no special lanes; pad lanes compute exactly 0 and write pad slots).
// Block's x tile staged once into LDS (fp32, stride 17) -> per-step broadcast
// ds_read, no global straggler. W pre-scaled (sigmoid rows -log2e, g rows
// +2log2e) so gates feed exp2 directly; W hi/lo fp16 (~exact), h fp16 plane.
// Two independent 2-MFMA chains + add (shorter dep path). One barrier/step.

#define NTH 832
#define TST 256
#define MB 16
#define NBLK 512
#define HR 72            // h row stride in halfs (16B-aligned b128 frag reads)
#define HSZ (MB * HR)    // 1152 halfs per buffer
#define XR 17            // x LDS row stride in floats (bank spread)

#define LOG2E 1.44269504088896f

typedef __attribute__((ext_vector_type(8))) _Float16 half8;
typedef __attribute__((ext_vector_type(4))) float float4v;

__device__ __forceinline__ float rcp_(float v)  { return __builtin_amdgcn_rcpf(v); }
__device__ __forceinline__ float exp2_(float v) { return __builtin_amdgcn_exp2f(v); }
__device__ __forceinline__ unsigned short f16bits(float v) {
    _Float16 h = (_Float16)v;                 // RNE
    return *(unsigned short*)&h;
}

__global__ __launch_bounds__(NTH, 7) void lstm_mfma(
    const float* __restrict__ x,      // [8192][256]
    const float* __restrict__ W_ih,   // [200]
    const float* __restrict__ W_hh,   // [200][50]
    const float* __restrict__ b_ih,   // [200]
    const float* __restrict__ b_hh,   // [200]
    const float* __restrict__ W_lin,  // [50]
    const float* __restrict__ b_lin,  // [1]
    float* __restrict__ out)          // [8192]
{
    __shared__ __align__(16) unsigned short Hh[2 * HSZ];   // fp16 h, double-buffered
    __shared__ __align__(16) float xs[TST * XR];           // x tile [t][b], 17.4 KB

    const int tid  = threadIdx.x;
    const int wv   = tid >> 6;      // 0..12 = tile T
    const int ln   = tid & 63;
    const int lrow = ln & 15;       // batch-in-block / A-row m / D col
    const int quad = ln >> 4;
    const int bbase = (int)blockIdx.x * MB;
    const int T = wv;
    const int ju = T * 4 + quad;    // unit this lane owns (0..51; >=50 = pad)

    // ---- W_hh fragments (one tile per wave; one-time L2 reads).
    // Row gr=T*16+lrow -> unit j=gr>>2, gate g=gr&3, W row = g*50+j.
    // k = q2*32 + quad*8 + i (k<50 real, else 0).
    // Pre-scale: sigmoid rows (g!=2) by -log2e, g rows by +2log2e.
    half8 wh[2], wl[2];
    {
        const int gr = T * 16 + lrow;
        const int j  = gr >> 2, g = gr & 3;
        const int row = g * 50 + j;             // only dereferenced when j<50
        const float scl = (g == 2) ? (2.0f * LOG2E) : (-LOG2E);
        #pragma unroll
        for (int q2 = 0; q2 < 2; ++q2) {
            half8 h8, l8;
            #pragma unroll
            for (int i = 0; i < 8; ++i) {
                const int k = q2 * 32 + quad * 8 + i;
                float V = (j < 50 && k < 50) ? W_hh[row * 50 + k] * scl : 0.0f;
                _Float16 hi = (_Float16)V;
                h8[i] = hi;
                l8[i] = (_Float16)(V - (float)hi);
            }
            wh[q2] = h8;
            wl[q2] = l8;
        }
    }

    // ---- per-lane x-weight & bias for this lane's unit, pre-scaled per gate
    float wihs[4], biass[4];
    #pragma unroll
    for (int g = 0; g < 4; ++g) {
        const float scl = (g == 2) ? (2.0f * LOG2E) : (-LOG2E);
        if (ju < 50) {
            wihs[g]  = W_ih[g * 50 + ju] * scl;
            biass[g] = (b_ih[g * 50 + ju] + b_hh[g * 50 + ju]) * scl;
        } else {
            wihs[g] = 0.0f; biass[g] = 0.0f;
        }
    }

    // ---- stage x tile: global [b][t] (coalesced float4) -> LDS xs[t][b]
    for (int idx = tid; idx < MB * TST / 4; idx += NTH) {   // 1024 float4s
        const int b  = idx >> 6;                 // 0..15
        const int t0 = (idx & 63) * 4;           // 0..252
        const float4 v4 = *(const float4*)&x[(bbase + b) * TST + t0];
        xs[(t0 + 0) * XR + b] = v4.x;
        xs[(t0 + 1) * XR + b] = v4.y;
        xs[(t0 + 2) * XR + b] = v4.z;
        xs[(t0 + 3) * XR + b] = v4.w;
    }
    // ---- init h: both buffers zero (h0 = 0; pad cols stay 0 forever)
    for (int i = tid; i < HSZ; i += NTH)         // HSZ uints = 2*HSZ halfs
        ((unsigned int*)Hh)[i] = 0u;
    __syncthreads();

    float c = 0.0f;
    const unsigned short* Hr = &Hh[lrow * HR + quad * 8];     // frag read base
    unsigned short*       Hw = &Hh[lrow * HR + ju];           // h write base
    const float*          Xr = &xs[lrow];                     // x read base
    const float4v z4 = {0.f, 0.f, 0.f, 0.f};                  // zero C operand

    // one LSTM step; roff/woff compile-time after inlining -> immediate offsets
    auto step1 = [&](int t, int roff, int woff) {
        const float xv = Xr[t * XR];             // broadcast ds_read_b32
        const half8 b0 = *(const half8*)(Hr + roff);
        const half8 b1 = *(const half8*)(Hr + roff + 32);

        float4v u, v;
        u = __builtin_amdgcn_mfma_f32_16x16x32_f16(wh[0], b0, z4, 0, 0, 0);
        v = __builtin_amdgcn_mfma_f32_16x16x32_f16(wl[0], b0, z4, 0, 0, 0);
        u = __builtin_amdgcn_mfma_f32_16x16x32_f16(wh[1], b1, u, 0, 0, 0);
        v = __builtin_amdgcn_mfma_f32_16x16x32_f16(wl[1], b1, v, 0, 0, 0);

        // a_g = W_hh.h + x*wihs + bias (all pre-scaled to feed exp2)
        const float a0 = fmaf(xv, wihs[0], u[0] + v[0]) + biass[0];
        const float a1 = fmaf(xv, wihs[1], u[1] + v[1]) + biass[1];
        const float a2 = fmaf(xv, wihs[2], u[2] + v[2]) + biass[2];
        const float a3 = fmaf(xv, wihs[3], u[3] + v[3]) + biass[3];

        // sigm = rcp(1+exp2(a)); tanh = 1-2*rcp(exp2(a)+1)
        const float i_ = rcp_(1.0f + exp2_(a0));
        const float f_ = rcp_(1.0f + exp2_(a1));
        const float g_ = fmaf(-2.0f, rcp_(exp2_(a2) + 1.0f), 1.0f);
        const float o_ = rcp_(1.0f + exp2_(a3));
        const float cn = f_ * c + i_ * g_;
        c = cn;
        const float th = fmaf(-2.0f, rcp_(exp2_(2.0f * LOG2E * cn) + 1.0f), 1.0f);
        const float hn = o_ * th;
        // pad lanes (ju>=50): a=0 -> g_=0, th=0 -> hn=0; write keeps pad zero.
        Hw[woff] = f16bits(hn);
        __syncthreads();                         // publish write buffer
    };

    #pragma unroll 1
    for (int t2 = 0; t2 < TST / 2; ++t2) {
        step1(2 * t2,     0,   HSZ);             // even: read buf0, write buf1
        step1(2 * t2 + 1, HSZ, 0);               // odd:  read buf1, write buf0
    }

    // ---- epilogue: final h in buf 0 (t=255 wrote buf0)
    if (tid < MB) {
        float s = b_lin[0];
        #pragma unroll 10
        for (int k = 0; k < 50; ++k) {
            float hk = (float)(*(const _Float16*)&Hh[tid * HR + k]);
            s += hk * W_lin[k];
        }
        out[bbase + tid] = s;
    }
}

extern "C" void kernel_launch(void* const* d_in, const int* in_sizes, int n_in,
                              void* d_out, int out_size, void* d_ws, size_t ws_size,
                              hipStream_t stream) {
    const float* x     = (const float*)d_in[0];
    const float* W_ih  = (const float*)d_in[1];
    const float* W_hh  = (const float*)d_in[2];
    const float* b_ih  = (const float*)d_in[3];
    const float* b_hh  = (const float*)d_in[4];
    const float* W_lin = (const float*)d_in[5];
    const float* b_lin = (const float*)d_in[6];
    float* out = (float*)d_out;

    lstm_mfma<<<dim3(NBLK), dim3(NTH), 0, stream>>>(
        x, W_ih, W_hh, b_ih, b_hh, W_lin, b_lin, out);
}

// Round 11
// 279.061 us; speedup vs baseline: 1.0269x; 1.0269x over previous
//
#include <hip/hip_runtime.h>

// LSTM B=8192,T=256,I=1,H=50 via MFMA, fp16 two-product, 13-wave split.
// R11 = R9 champion + x tile resident in LDS (fp16, staged once) so the
// t-loop has ZERO global memory ops -> no vmcnt drain at barriers, no
// wave-12 straggler. (R10 post-mortem: folding x/bias onto VALU regressed;
// keep x and bias inside the GEMM as columns k=50/51 -- MFMA pipe has slack.)
// Per block: 16 batches, 13 waves (NTH=832), wave wv owns tile T=wv.
// Per step: D[208x16] = W[208x64] x h[64x16]; rows = unit*4+gate
// (50 real units + x-col k=50 + bias-col k=51), cols = batches.
// C/D layout: lane (lrow=ln&15, quad=ln>>4) of wave T gets the 4 gates of
// (batch=lrow, unit=4T+quad) in its 4 acc regs -> activations in-register.
// W pre-scaled (sigmoid rows by -log2e, g rows by +2log2e) so gates feed
// exp2 directly; W split hi/lo fp16 (~exact), h single fp16 plane.
// h double-buffered, ONE barrier/step. 512 blocks x 13 waves = 26 waves/CU.

#define NTH 832
#define TST 256
#define MB 16
#define NBLK 512
#define HR 72            // h row stride in halfs (16B-aligned b128 frag reads)
#define HSZ (MB * HR)    // 1152 halfs per buffer
#define XR 17            // x tile row stride in halfs

#define LOG2E 1.44269504088896f

typedef __attribute__((ext_vector_type(8))) _Float16 half8;
typedef __attribute__((ext_vector_type(4))) float float4v;

__device__ __forceinline__ float rcp_(float v)  { return __builtin_amdgcn_rcpf(v); }
__device__ __forceinline__ float exp2_(float v) { return __builtin_amdgcn_exp2f(v); }
__device__ __forceinline__ unsigned short f16bits(float v) {
    _Float16 h = (_Float16)v;                 // RNE
    return *(unsigned short*)&h;
}

__global__ __launch_bounds__(NTH, 7) void lstm_mfma(
    const float* __restrict__ x,      // [8192][256]
    const float* __restrict__ W_ih,   // [200]
    const float* __restrict__ W_hh,   // [200][50]
    const float* __restrict__ b_ih,   // [200]
    const float* __restrict__ b_hh,   // [200]
    const float* __restrict__ W_lin,  // [50]
    const float* __restrict__ b_lin,  // [1]
    float* __restrict__ out)          // [8192]
{
    __shared__ __align__(16) unsigned short Hh[2 * HSZ];   // fp16 h, double-buffered
    __shared__ __align__(16) unsigned short xt[TST * XR];  // fp16 x tile [t][b], 8.7 KB

    const int tid  = threadIdx.x;
    const int wv   = tid >> 6;      // 0..12 = tile T
    const int ln   = tid & 63;
    const int lrow = ln & 15;       // batch-in-block / A-row m / D col
    const int quad = ln >> 4;
    const int bbase = (int)blockIdx.x * MB;
    const int T = wv;

    // ---- W-operand fragments (one tile per wave; one-time L2 reads).
    // Row gr=T*16+lrow -> unit j=gr>>2, gate g=gr&3, W row = g*50+j.
    // k = q2*32 + quad*8 + i; k=50 -> W_ih, k=51 -> bias; pad rows (j>=50) zero.
    // Pre-scale: sigmoid rows (g!=2) by -log2e, g rows by +2log2e.
    half8 wh[2], wl[2];
    {
        const int gr = T * 16 + lrow;
        const int j  = gr >> 2, g = gr & 3;
        const int row = g * 50 + j;             // only dereferenced when j<50
        const float scl = (g == 2) ? (2.0f * LOG2E) : (-LOG2E);
        #pragma unroll
        for (int q2 = 0; q2 < 2; ++q2) {
            half8 h8, l8;
            #pragma unroll
            for (int i = 0; i < 8; ++i) {
                const int k = q2 * 32 + quad * 8 + i;
                float V = 0.0f;
                if (j < 50) {
                    if (k < 50)       V = W_hh[row * 50 + k];
                    else if (k == 50) V = W_ih[row];
                    else if (k == 51) V = b_ih[row] + b_hh[row];
                }
                V *= scl;
                _Float16 hi = (_Float16)V;
                h8[i] = hi;
                l8[i] = (_Float16)(V - (float)hi);
            }
            wh[q2] = h8;
            wl[q2] = l8;
        }
    }

    // ---- stage x tile once: global [b][t] (coalesced float4) -> fp16 xt[t][b]
    for (int idx = tid; idx < MB * TST / 4; idx += NTH) {   // 1024 float4s
        const int b  = idx >> 6;                 // 0..15
        const int t0 = (idx & 63) * 4;           // 0..252
        const float4 v4 = *(const float4*)&x[(bbase + b) * TST + t0];
        xt[(t0 + 0) * XR + b] = f16bits(v4.x);
        xt[(t0 + 1) * XR + b] = f16bits(v4.y);
        xt[(t0 + 2) * XR + b] = f16bits(v4.z);
        xt[(t0 + 3) * XR + b] = f16bits(v4.w);
    }
    // ---- init h: zeros (both bufs); k=51 <- fp16(1.0) BOTH bufs; k=50 of
    // buf0 <- fp16(x(b,0)) (written after barrier from the staged tile)
    for (int i = tid; i < HSZ; i += NTH)         // HSZ uints = 2*HSZ halfs
        ((unsigned int*)Hh)[i] = 0u;
    __syncthreads();
    if (tid < MB) {
        Hh[tid * HR + 50] = xt[0 * XR + tid];    // x(b,0)
        Hh[tid * HR + 51] = 0x3C00;              // fp16(1.0), never rewritten
        Hh[HSZ + tid * HR + 51] = 0x3C00;
    }
    __syncthreads();

    float c = 0.0f;
    const unsigned short* Hr = &Hh[lrow * HR + quad * 8];     // frag read base
    unsigned short*       Hw = &Hh[lrow * HR + T * 4 + quad]; // write base
    const unsigned short* Xr = &xt[lrow];                     // wave-12 x base
    const bool xlane   = (wv == 12) && (quad == 2);           // k=50 column owner
    const bool skiplan = (wv == 12) && (quad == 3);           // k=51 constant col
    const float4v z4 = {0.f, 0.f, 0.f, 0.f};                  // zero C operand

    // one LSTM step; roff/woff compile-time after inlining -> immediate offsets
    auto step1 = [&](int roff, int woff, unsigned short xbits) {
        const half8 b0 = *(const half8*)(Hr + roff);
        const half8 b1 = *(const half8*)(Hr + roff + 32);

        float4v a4;
        a4 = __builtin_amdgcn_mfma_f32_16x16x32_f16(wh[0], b0, z4, 0, 0, 0);
        a4 = __builtin_amdgcn_mfma_f32_16x16x32_f16(wh[1], b1, a4, 0, 0, 0);
        a4 = __builtin_amdgcn_mfma_f32_16x16x32_f16(wl[0], b0, a4, 0, 0, 0);
        a4 = __builtin_amdgcn_mfma_f32_16x16x32_f16(wl[1], b1, a4, 0, 0, 0);

        // gates pre-scaled: sigm = rcp(1+exp2(a)); tanh = 1-2*rcp(exp2(a)+1)
        float i_ = rcp_(1.0f + exp2_(a4[0]));
        float f_ = rcp_(1.0f + exp2_(a4[1]));
        float g_ = fmaf(-2.0f, rcp_(exp2_(a4[2]) + 1.0f), 1.0f);
        float o_ = rcp_(1.0f + exp2_(a4[3]));
        float cn = f_ * c + i_ * g_;
        c = cn;
        float th = fmaf(-2.0f, rcp_(exp2_(2.0f * LOG2E * cn) + 1.0f), 1.0f);
        float hn = o_ * th;

        unsigned short hb = f16bits(hn);
        if (xlane) hb = xbits;                 // k=50 column <- fp16(x(t+1))
        if (!skiplan)
            Hw[woff] = hb;
        __syncthreads();                       // publish write buffer (lgkm only:
                                               // no global ops pending in-loop)
    };

    #pragma unroll 1
    for (int t2 = 0; t2 < TST / 2; ++t2) {
        const int t = t2 * 2;
        unsigned short xA = 0, xB = 0;
        if (wv == 12) {                        // broadcast ds_read_u16 x2
            xA = Xr[(t + 1) * XR];
            xB = Xr[((t + 2) & 255) * XR];     // t=254: row 0, value never read
        }
        step1(0,   HSZ, xA);                   // even step: read buf0, write buf1
        step1(HSZ, 0,   xB);                   // odd  step: read buf1, write buf0
    }

    // ---- epilogue: final h in buf 0 (t=255 wrote buf0)
    if (tid < MB) {
        float s = b_lin[0];
        #pragma unroll 10
        for (int k = 0; k < 50; ++k) {
            float hk = (float)(*(const _Float16*)&Hh[tid * HR + k]);
            s += hk * W_lin[k];
        }
        out[bbase + tid] = s;
    }
}

extern "C" void kernel_launch(void* const* d_in, const int* in_sizes, int n_in,
                              void* d_out, int out_size, void* d_ws, size_t ws_size,
                              hipStream_t stream) {
    const float* x     = (const float*)d_in[0];
    const float* W_ih  = (const float*)d_in[1];
    const float* W_hh  = (const float*)d_in[2];
    const float* b_ih  = (const float*)d_in[3];
    const float* b_hh  = (const float*)d_in[4];
    const float* W_lin = (const float*)d_in[5];
    const float* b_lin = (const float*)d_in[6];
    float* out = (float*)d_out;

    lstm_mfma<<<dim3(NBLK), dim3(NTH), 0, stream>>>(
        x, W_ih, W_hh, b_ih, b_hh, W_lin, b_lin, out);
}

// Round 12
// 225.745 us; speedup vs baseline: 1.2694x; 1.2362x over previous
//
#include <hip/hip_runtime.h>

// LSTM B=8192,T=256,I=1,H=50 via MFMA, fp16 two-product, 13+1-wave split.
// R12 = R9 champion + dedicated x-wave + pad-redirect stores.
//   - R10/R11 post-mortem: SGPR 96 broke 2-blocks/CU co-residency (8 waves x
//     96 SGPR ~ SIMD pool) -> keep footprint at R9 level (VGPR~20, SGPR~32).
//   - Wave 13 (NTH=896) owns ONLY the k=50 x-column: prefetches x(t+1)/x(t+2)
//     at iteration top (latency hidden -- it has no other work) and writes
//     fp16 x into the next h-buffer. Compute waves 0..12: ZERO global ops,
//     ZERO conditionals in the t-loop.
//   - Lanes with unit>=50 (wave 12 quads 2/3) store to pad slots 54/55 in the
//     HR=72 row -> unconditional ds_write for every lane, set up pre-loop.
// Per block: 16 batches; wave wv (0..12) owns tile T=wv. Per step:
// D[208x16] = W[208x64] x h[64x16]; rows = unit*4+gate (50 real units +
// x-col k=50 + bias-col k=51), cols = batches. C/D layout: lane
// (lrow=ln&15, quad=ln>>4) of wave T gets gates (i,f,g,o) of
// (batch=lrow, unit=4T+quad) in its 4 acc regs -> activations in-register.
// W pre-scaled (sigmoid rows by -log2e, g rows by +2log2e) so gates feed
// exp2 directly; W split hi/lo fp16 (~exact), h single fp16 plane.
// h double-buffered, ONE barrier/step. 512 blocks x 14 waves = 28 waves/CU.

#define NTH 896
#define TST 256
#define MB 16
#define NBLK 512
#define HR 72            // h row stride in halfs (16B-aligned b128 frag reads)
#define HSZ (MB * HR)    // 1152 halfs per buffer

#define LOG2E 1.44269504088896f

typedef __attribute__((ext_vector_type(8))) _Float16 half8;
typedef __attribute__((ext_vector_type(4))) float float4v;

__device__ __forceinline__ float rcp_(float v)  { return __builtin_amdgcn_rcpf(v); }
__device__ __forceinline__ float exp2_(float v) { return __builtin_amdgcn_exp2f(v); }
__device__ __forceinline__ unsigned short f16bits(float v) {
    _Float16 h = (_Float16)v;                 // RNE
    return *(unsigned short*)&h;
}

__global__ __launch_bounds__(NTH, 7) void lstm_mfma(
    const float* __restrict__ x,      // [8192][256]
    const float* __restrict__ W_ih,   // [200]
    const float* __restrict__ W_hh,   // [200][50]
    const float* __restrict__ b_ih,   // [200]
    const float* __restrict__ b_hh,   // [200]
    const float* __restrict__ W_lin,  // [50]
    const float* __restrict__ b_lin,  // [1]
    float* __restrict__ out)          // [8192]
{
    __shared__ __align__(16) unsigned short Hh[2 * HSZ];   // fp16 h, double-buffered

    const int tid  = threadIdx.x;
    const int wv   = tid >> 6;      // 0..12 = tile T; 13 = x-wave
    const int ln   = tid & 63;
    const int lrow = ln & 15;       // batch-in-block / A-row m / D col
    const int quad = ln >> 4;
    const int bbase = (int)blockIdx.x * MB;
    const int T = wv;

    // ---- W-operand fragments (one tile per wave; one-time L2 reads).
    // Row gr=T*16+lrow -> unit j=gr>>2, gate g=gr&3, W row = g*50+j.
    // k = q2*32 + quad*8 + i; k=50 -> W_ih, k=51 -> bias; pad rows (j>=50)
    // zero (incl. all of wave 13 -- it never issues MFMA anyway).
    // Pre-scale: sigmoid rows (g!=2) by -log2e, g rows by +2log2e.
    half8 wh[2], wl[2];
    {
        const int gr = T * 16 + lrow;
        const int j  = gr >> 2, g = gr & 3;
        const int row = g * 50 + j;             // only dereferenced when j<50
        const float scl = (g == 2) ? (2.0f * LOG2E) : (-LOG2E);
        #pragma unroll
        for (int q2 = 0; q2 < 2; ++q2) {
            half8 h8, l8;
            #pragma unroll
            for (int i = 0; i < 8; ++i) {
                const int k = q2 * 32 + quad * 8 + i;
                float V = 0.0f;
                if (j < 50) {
                    if (k < 50)       V = W_hh[row * 50 + k];
                    else if (k == 50) V = W_ih[row];
                    else if (k == 51) V = b_ih[row] + b_hh[row];
                }
                V *= scl;
                _Float16 hi = (_Float16)V;
                h8[i] = hi;
                l8[i] = (_Float16)(V - (float)hi);
            }
            wh[q2] = h8;
            wl[q2] = l8;
        }
    }

    // ---- init h: zeros both bufs; k=50 buf0 <- fp16(x(b,0)); k=51 <- 1.0 both
    for (int i = tid; i < HSZ; i += NTH)       // HSZ uints = 2*HSZ halfs
        ((unsigned int*)Hh)[i] = 0u;
    __syncthreads();
    if (tid < MB) {
        float xv = x[(bbase + tid) * TST + 0];
        Hh[tid * HR + 50] = f16bits(xv);
        Hh[tid * HR + 51] = 0x3C00;            // fp16(1.0), never rewritten
        Hh[HSZ + tid * HR + 51] = 0x3C00;
    }
    __syncthreads();

    float c = 0.0f;
    const unsigned short* Hr = &Hh[lrow * HR + quad * 8];  // frag read base
    int jw = T * 4 + quad;                                 // unit this lane writes
    if (jw >= 50) jw = 52 + quad;                          // pad redirect (54/55)
    unsigned short* Hw = &Hh[lrow * HR + jw];              // write base (hoisted)
    const float* xr = &x[(bbase + lrow) * TST];            // x-wave read row
    const float4v z4 = {0.f, 0.f, 0.f, 0.f};               // zero C operand

    // one compute step; roff/woff compile-time after inlining -> imm offsets
    auto step1 = [&](int roff, int woff) {
        const half8 b0 = *(const half8*)(Hr + roff);
        const half8 b1 = *(const half8*)(Hr + roff + 32);

        float4v a4;
        a4 = __builtin_amdgcn_mfma_f32_16x16x32_f16(wh[0], b0, z4, 0, 0, 0);
        a4 = __builtin_amdgcn_mfma_f32_16x16x32_f16(wh[1], b1, a4, 0, 0, 0);
        a4 = __builtin_amdgcn_mfma_f32_16x16x32_f16(wl[0], b0, a4, 0, 0, 0);
        a4 = __builtin_amdgcn_mfma_f32_16x16x32_f16(wl[1], b1, a4, 0, 0, 0);

        // gates pre-scaled: sigm = rcp(1+exp2(a)); tanh = 1-2*rcp(exp2(a)+1)
        float i_ = rcp_(1.0f + exp2_(a4[0]));
        float f_ = rcp_(1.0f + exp2_(a4[1]));
        float g_ = fmaf(-2.0f, rcp_(exp2_(a4[2]) + 1.0f), 1.0f);
        float o_ = rcp_(1.0f + exp2_(a4[3]));
        float cn = f_ * c + i_ * g_;
        c = cn;
        float th = fmaf(-2.0f, rcp_(exp2_(2.0f * LOG2E * cn) + 1.0f), 1.0f);
        float hn = o_ * th;

        Hw[woff] = f16bits(hn);                // unconditional (pad-redirected)
    };

    #pragma unroll 1
    for (int t2 = 0; t2 < TST / 2; ++t2) {
        if (wv == 13) {
            // x-wave: prefetch both x values at iteration top (latency hidden),
            // publish fp16(x(t+1)) into the buffer the NEXT step will read.
            const float xA = xr[2 * t2 + 1];
            const float xB = xr[(2 * t2 + 2) & 255];   // t2=127: never read
            if (ln < 16)
                Hh[HSZ + lrow * HR + 50] = f16bits(xA);   // buf1 <- x(odd step)
            __syncthreads();                   // barrier 1 (even step done)
            if (ln < 16)
                Hh[lrow * HR + 50] = f16bits(xB);         // buf0 <- x(even step)
            __syncthreads();                   // barrier 2 (odd step done)
        } else {
            step1(0, HSZ);                     // even: read buf0, write buf1
            __syncthreads();
            step1(HSZ, 0);                     // odd:  read buf1, write buf0
            __syncthreads();
        }
    }

    // ---- epilogue: final h in buf 0 (t=255 wrote buf0)
    if (tid < MB) {
        float s = b_lin[0];
        #pragma unroll 10
        for (int k = 0; k < 50; ++k) {
            float hk = (float)(*(const _Float16*)&Hh[tid * HR + k]);
            s += hk * W_lin[k];
        }
        out[bbase + tid] = s;
    }
}

extern "C" void kernel_launch(void* const* d_in, const int* in_sizes, int n_in,
                              void* d_out, int out_size, void* d_ws, size_t ws_size,
                              hipStream_t stream) {
    const float* x     = (const float*)d_in[0];
    const float* W_ih  = (const float*)d_in[1];
    const float* W_hh  = (const float*)d_in[2];
    const float* b_ih  = (const float*)d_in[3];
    const float* b_hh  = (const float*)d_in[4];
    const float* W_lin = (const float*)d_in[5];
    const float* b_lin = (const float*)d_in[6];
    float* out = (float*)d_out;

    lstm_mfma<<<dim3(NBLK), dim3(NTH), 0, stream>>>(
        x, W_ih, W_hh, b_ih, b_hh, W_lin, b_lin, out);
}